// Round 1
// baseline (100.690 us; speedup 1.0000x reference)
//
#include <hip/hip_runtime.h>

// DynFilter3D: out[b,h,w,o] = sum_{i,j,t} x[b,t,h+i-1,w+j-1] * f[b,h,w,(i*9+j*3+t),o]
// x: (B=8, T=3, H=192, W=192) f32   f: (B,H,W,27,16) f32   out: (B,H,W,16) f32
// Memory-bound: f (509.6 MB) streamed exactly once. 4 threads/pixel, float4 per thread.

#define B_ 8
#define T_ 3
#define H_ 192
#define W_ 192
#define CO_ 16
#define KT_ 27   // 3*3*3 taps

__global__ __launch_bounds__(256) void DynFilter3D_kernel(
    const float* __restrict__ x,
    const float* __restrict__ f,
    float* __restrict__ out,
    int npix)
{
    int g = blockIdx.x * blockDim.x + threadIdx.x;
    int pix = g >> 2;        // pixel index (b*H + h)*W + w
    int t4  = g & 3;         // which float4 of the 16 output channels
    if (pix >= npix) return;

    int w   = pix % W_;
    int bh  = pix / W_;
    int h   = bh % H_;
    int b   = bh / H_;

    // ---- gather the 27 patch values (zero padded SAME), order k = i*9 + j*3 + t ----
    float patches[KT_];
    const float* xb = x + (size_t)b * (T_ * H_ * W_);
#pragma unroll
    for (int i = 0; i < 3; ++i) {
        int hh = h + i - 1;
        bool hin = (unsigned)hh < (unsigned)H_;
#pragma unroll
        for (int j = 0; j < 3; ++j) {
            int ww = w + j - 1;
            bool in = hin && ((unsigned)ww < (unsigned)W_);
#pragma unroll
            for (int t = 0; t < 3; ++t) {
                float v = 0.0f;
                if (in) v = xb[(size_t)(t * H_ + hh) * W_ + ww];
                patches[(i * 3 + j) * 3 + t] = v;
            }
        }
    }

    // ---- stream this pixel's f block: 27 x float4 at stride 4 float4s ----
    const float4* fb = reinterpret_cast<const float4*>(f + (size_t)pix * (KT_ * CO_));
    float4 acc = make_float4(0.f, 0.f, 0.f, 0.f);
#pragma unroll
    for (int k = 0; k < KT_; ++k) {
        float4 fv = fb[k * 4 + t4];
        float  p  = patches[k];
        acc.x = fmaf(p, fv.x, acc.x);
        acc.y = fmaf(p, fv.y, acc.y);
        acc.z = fmaf(p, fv.z, acc.z);
        acc.w = fmaf(p, fv.w, acc.w);
    }

    reinterpret_cast<float4*>(out + (size_t)pix * CO_)[t4] = acc;
}

extern "C" void kernel_launch(void* const* d_in, const int* in_sizes, int n_in,
                              void* d_out, int out_size, void* d_ws, size_t ws_size,
                              hipStream_t stream) {
    const float* x = (const float*)d_in[0];   // 8*3*192*192
    const float* f = (const float*)d_in[1];   // 8*192*192*27*16
    float* out = (float*)d_out;               // 8*192*192*16

    const int npix = B_ * H_ * W_;            // 294912
    const int nthreads = npix * 4;            // 1,179,648
    const int block = 256;
    const int grid = (nthreads + block - 1) / block;  // 4608
    DynFilter3D_kernel<<<grid, block, 0, stream>>>(x, f, out, npix);
}

// Round 2
// 98.749 us; speedup vs baseline: 1.0197x; 1.0197x over previous
//
#include <hip/hip_runtime.h>

// DynFilter3D: out[b,h,w,o] = sum_{i,j,t} x[b,t,h+i-1,w+j-1] * f[b,h,w,(i*9+j*3+t),o]
// x: (B=8, T=3, H=192, W=192) f32   f: (B,H,W,27,16) f32   out: (B,H,W,16) f32
// Memory-bound: f (509.6 MB) streamed exactly once (~84.5us floor at 6.3 TB/s).
// Block = 64 consecutive pixels of one image row; x patch halo staged in LDS
// so the vmcnt queue holds ONLY the 27 streaming f loads per thread.

#define B_ 8
#define T_ 3
#define H_ 192
#define W_ 192
#define CO_ 16
#define KT_ 27          // 3*3*3 taps
#define PIX_PER_BLK 64  // one row segment; W = 3 * 64
#define XS_N (3 * 3 * 66)  // [t][i][ww'] halo tile

__global__ __launch_bounds__(256) void DynFilter3D_kernel(
    const float* __restrict__ x,
    const float* __restrict__ f,
    float* __restrict__ out)
{
    // block -> (b, h, wt); 64 pixels at w0 = wt*64, 4 threads/pixel
    int blk = blockIdx.x;
    int wt  = blk % 3;
    int bh  = blk / 3;
    int h   = bh % H_;
    int b   = bh / H_;
    int w0  = wt * PIX_PER_BLK;

    __shared__ float xs[XS_N];  // [t][i][66], ww' = w - w0 + 1

    // ---- stage x halo: 594 floats, coalesced, 3 rounds of 256 threads ----
    for (int idx = threadIdx.x; idx < XS_N; idx += 256) {
        int wwp = idx % 66;
        int ti  = idx / 66;      // t*3 + i
        int i   = ti % 3;
        int t   = ti / 3;
        int hh  = h + i - 1;
        int ww  = w0 + wwp - 1;
        float v = 0.0f;
        if ((unsigned)hh < (unsigned)H_ && (unsigned)ww < (unsigned)W_)
            v = x[(size_t)((b * T_ + t) * H_ + hh) * W_ + ww];
        xs[idx] = v;
    }
    __syncthreads();

    int wl = threadIdx.x >> 2;   // local pixel 0..63
    int t4 = threadIdx.x & 3;    // which float4 of 16 channels

    // ---- patches from LDS (broadcast reads, no vmcnt traffic) ----
    float patches[KT_];
#pragma unroll
    for (int i = 0; i < 3; ++i)
#pragma unroll
        for (int j = 0; j < 3; ++j)
#pragma unroll
            for (int t = 0; t < 3; ++t)
                patches[(i * 3 + j) * 3 + t] = xs[(t * 3 + i) * 66 + wl + j];

    // ---- stream this pixel's f block: 27 x float4, pure vmcnt pipeline ----
    size_t pix = (size_t)(b * H_ + h) * W_ + w0 + wl;
    const float4* fb = reinterpret_cast<const float4*>(f + pix * (KT_ * CO_));
    float4 acc = make_float4(0.f, 0.f, 0.f, 0.f);
#pragma unroll
    for (int k = 0; k < KT_; ++k) {
        float4 fv = fb[k * 4 + t4];
        float  p  = patches[k];
        acc.x = fmaf(p, fv.x, acc.x);
        acc.y = fmaf(p, fv.y, acc.y);
        acc.z = fmaf(p, fv.z, acc.z);
        acc.w = fmaf(p, fv.w, acc.w);
    }

    reinterpret_cast<float4*>(out + pix * CO_)[t4] = acc;
}

extern "C" void kernel_launch(void* const* d_in, const int* in_sizes, int n_in,
                              void* d_out, int out_size, void* d_ws, size_t ws_size,
                              hipStream_t stream) {
    const float* x = (const float*)d_in[0];   // 8*3*192*192
    const float* f = (const float*)d_in[1];   // 8*192*192*27*16
    float* out = (float*)d_out;               // 8*192*192*16

    const int grid = B_ * H_ * 3;             // 4608 blocks, 64 pixels each
    DynFilter3D_kernel<<<grid, 256, 0, stream>>>(x, f, out);
}